// Round 4
// baseline (1596.462 us; speedup 1.0000x reference)
//
#include <hip/hip_runtime.h>

#define N_NODE 10000
#define N_EDGE 40000
#define N_LAYER 15

typedef unsigned short U16;
typedef __attribute__((ext_vector_type(8))) short short8;
typedef __attribute__((ext_vector_type(4))) float f32x4;

enum { A_BF16 = 0, A_EDGE, A_NODE, A_ENCIN, A_ERAW };
enum { EPI_F = 0, EPI_EDGE, EPI_NODE, EPI_DEC };

// Wt layout offsets (bf16 elements), [n=128][Kpad] per matrix
#define OFF_FV1 0
#define OFF_FV2 4096
#define OFF_FV3 20480
#define OFF_FE1 36864
#define OFF_FE2 40960
#define OFF_FE3 57344
#define OFF_GE1 73728     /* stride 49152 (Kpad=384) */
#define OFF_GE2 811008    /* stride 16384 */
#define OFF_GE3 1056768
#define OFF_GN1 1302528   /* stride 32768 (Kpad=256) */
#define OFF_GN2 1794048
#define OFF_GN3 2039808
#define OFF_DE1 2285568
#define OFF_DE2 2301952
#define WT_TOTAL 2318336

static __device__ __forceinline__ U16 f2b(float f) {
    union { float f; unsigned u; } x; x.f = f;
    unsigned u = x.u;
    return (U16)((u + 0x7fffu + ((u >> 16) & 1u)) >> 16);
}
static __device__ __forceinline__ float b2f(U16 u) {
    union { unsigned u; float f; } x; x.u = ((unsigned)u) << 16;
    return x.f;
}

// workgroup barrier draining ONLY lgkmcnt (ds ops); global loads in flight
// (vmcnt) survive it.
static __device__ __forceinline__ void wgb() {
    __asm__ __volatile__("s_waitcnt lgkmcnt(0)\n\ts_barrier" ::: "memory");
}

// ---------------- weight transpose+cast: W[K][128] f32 -> Wt[n][Kpad] bf16 ----
__global__ __launch_bounds__(256)
void wprep(const float* fv1, const float* fv2, const float* fv3,
           const float* fe1, const float* fe2, const float* fe3,
           const float* ge1, const float* ge2, const float* ge3,
           const float* gn1, const float* gn2, const float* gn3,
           const float* de1, const float* de2, U16* Wt)
{
    int b = blockIdx.x;
    const float* src; U16* dst; int K, Kpad, k0;
    if      (b < 1)   { src = fv1; K = 12;  Kpad = 32;  dst = Wt + OFF_FV1; k0 = b * 32; }
    else if (b < 5)   { src = fv2; K = 128; Kpad = 128; dst = Wt + OFF_FV2; k0 = (b-1)*32; }
    else if (b < 9)   { src = fv3; K = 128; Kpad = 128; dst = Wt + OFF_FV3; k0 = (b-5)*32; }
    else if (b < 10)  { src = fe1; K = 4;   Kpad = 32;  dst = Wt + OFF_FE1; k0 = (b-9)*32; }
    else if (b < 14)  { src = fe2; K = 128; Kpad = 128; dst = Wt + OFF_FE2; k0 = (b-10)*32; }
    else if (b < 18)  { src = fe3; K = 128; Kpad = 128; dst = Wt + OFF_FE3; k0 = (b-14)*32; }
    else if (b < 198) { int r = b-18,  mi = r/12, s = r%12; src = ge1 + (size_t)mi*384*128; K = 384; Kpad = 384; dst = Wt + OFF_GE1 + (size_t)mi*49152; k0 = s*32; }
    else if (b < 258) { int r = b-198, mi = r/4,  s = r%4;  src = ge2 + (size_t)mi*16384;   K = 128; Kpad = 128; dst = Wt + OFF_GE2 + (size_t)mi*16384; k0 = s*32; }
    else if (b < 318) { int r = b-258, mi = r/4,  s = r%4;  src = ge3 + (size_t)mi*16384;   K = 128; Kpad = 128; dst = Wt + OFF_GE3 + (size_t)mi*16384; k0 = s*32; }
    else if (b < 438) { int r = b-318, mi = r/8,  s = r%8;  src = gn1 + (size_t)mi*32768;   K = 256; Kpad = 256; dst = Wt + OFF_GN1 + (size_t)mi*32768; k0 = s*32; }
    else if (b < 498) { int r = b-438, mi = r/4,  s = r%4;  src = gn2 + (size_t)mi*16384;   K = 128; Kpad = 128; dst = Wt + OFF_GN2 + (size_t)mi*16384; k0 = s*32; }
    else if (b < 558) { int r = b-498, mi = r/4,  s = r%4;  src = gn3 + (size_t)mi*16384;   K = 128; Kpad = 128; dst = Wt + OFF_GN3 + (size_t)mi*16384; k0 = s*32; }
    else if (b < 562) { src = de1; K = 128; Kpad = 128; dst = Wt + OFF_DE1; k0 = (b-558)*32; }
    else              { src = de2; K = 128; Kpad = 128; dst = Wt + OFF_DE2; k0 = (b-562)*32; }

    __shared__ float T[32][129];
    #pragma unroll
    for (int i = 0; i < 16; ++i) {
        int l = threadIdx.x + i * 256;
        int kk = l >> 7, n = l & 127;
        int kg = k0 + kk;
        T[kk][n] = (kg < K) ? src[(size_t)kg * 128 + n] : 0.f;
    }
    __syncthreads();
    int n = threadIdx.x >> 1, h = threadIdx.x & 1;
    union { U16 u[16]; int4 v[2]; } o;
    #pragma unroll
    for (int j = 0; j < 16; ++j) o.u[j] = f2b(T[h * 16 + j][n]);
    int4* d = (int4*)(dst + (size_t)n * Kpad + k0 + h * 16);
    d[0] = o.v[0]; d[1] = o.v[1];
}

// ---------------- CSR build (sender-sorted positions) ------------------------
__global__ __launch_bounds__(256)
void csr_hist(const int* __restrict__ edges, int* __restrict__ cnt, int Eg)
{
    int e = blockIdx.x * 256 + threadIdx.x;
    if (e < Eg) atomicAdd(&cnt[edges[2 * e]], 1);
}

__global__ __launch_bounds__(256)
void csr_scan(const int* __restrict__ cnt, int* __restrict__ rowptr,
              int* __restrict__ cursor, int n)
{
    __shared__ int ps[256];
    int t = threadIdx.x, base = t * 40;
    int s = 0;
    for (int j = 0; j < 40; ++j) if (base + j < n) s += cnt[base + j];
    ps[t] = s; __syncthreads();
    for (int off = 1; off < 256; off <<= 1) {
        int v = (t >= off) ? ps[t - off] : 0;
        __syncthreads();
        ps[t] += v;
        __syncthreads();
    }
    int run = ps[t] - s;   // exclusive prefix
    for (int j = 0; j < 40; ++j) {
        if (base + j < n) {
            rowptr[base + j] = run;
            cursor[base + j] = run;
            run += cnt[base + j];
        }
    }
    if (t == 255) rowptr[n] = ps[255];
}

// spos[e] = position of edge e in the sender-sorted order
__global__ __launch_bounds__(256)
void csr_scatter(const int* __restrict__ edges, int* __restrict__ cursor,
                 int* __restrict__ spos, int Eg)
{
    int e = blockIdx.x * 256 + threadIdx.x;
    if (e < Eg) spos[e] = atomicAdd(&cursor[edges[2 * e]], 1);
}

// ---------------- fused 3-layer MLP: barrier-free register-direct K-loops ----
// R3 showed the old structure latency-bound by ~20 barrier-chained K-chunks
// per block (MfmaUtil 4.8%, VALUBusy 5.9%, HBM 20% -- all pipes idle). Here
// W and A MFMA fragments are loaded DIRECTLY from global/L2 into registers in
// fragment layout (weights are pre-transposed [n][Kpad], L2-resident), with a
// depth-2 register ping-pong and NO intra-phase barriers: the only waits are
// per-wave counted vmcnt. Barriers remain only at phase transitions (the Hs
// activation exchange is genuinely inter-wave) and after the node-agg
// staging: 3-4 per block instead of ~20. 8 waves = 2 m x 4 n; wave tile =
// (16*NAG) m-rows x 32 n-cols. The 4 n-waves redundantly re-load A from L2
// (+~2us of L2 traffic) -- the price of deleting the barriers. Node-kernel
// segmented sum is still computed once (LDS-staged pre-phase-1) to keep the
// serial random-read chain off 4x duplication (R2 lesson).
template<int ASRC, int EPI, int K1, int BM>
__global__ __launch_bounds__(512, 4)
void mlp3(const U16* __restrict__ Af,
          const U16* __restrict__ W1, const float* __restrict__ b1,
          const U16* __restrict__ W2, const float* __restrict__ b2,
          const U16* __restrict__ W3, const float* __restrict__ b3,
          U16* __restrict__ outh, float* __restrict__ outf,
          const int* __restrict__ edges, const int* __restrict__ rowptr,
          const int* __restrict__ spos, float* __restrict__ eEs,
          const U16* __restrict__ Vh, const U16* __restrict__ Ehp,
          const float* __restrict__ pos, const float* __restrict__ area,
          const float* __restrict__ info, const float* __restrict__ w3f,
          const float* __restrict__ lng, const float* __restrict__ lnbp,
          int M)
{
    constexpr int NAG = BM / 32;              // A fragments per wave (m-dir)
    constexpr int C1  = K1 / 32;
    constexpr int HSB = BM * 132 * 2;                          // Hs bytes
    constexpr int AGB = (ASRC == A_NODE) ? BM * 132 * 2 : 0;   // agg stage
    constexpr int LNBY = (EPI == EPI_F) ? BM * 128 * 4 : 0;    // LN buffer
    __shared__ __align__(16) char smem[HSB + AGB + LNBY];
    auto Hs  = (U16 (*)[132])smem;            // [BM][132] inter-phase acts
    auto AG  = (U16 (*)[132])(smem + HSB);    // [BM][132] node agg (A_NODE)
    auto LNb = (float (*)[128])(smem + HSB);  // [BM][128] EPI_F only

    const int tid  = threadIdx.x;
    const int row0 = blockIdx.x * BM;
    const int wave = tid >> 6, lane = tid & 63;
    const int quad = lane >> 4, l16 = lane & 15;
    const int wm = (wave >> 2) * (16 * NAG);   // wave m-offset
    const int wn = (wave & 3) * 32;            // wave n-offset (0/32/64/96)
    const int wrow0 = wn + l16, wrow1 = wn + 16 + l16;   // W fragment rows

    // per-ag row metadata
    int mloc[NAG], mg[NAG]; bool mv[NAG];
    #pragma unroll
    for (int g = 0; g < NAG; ++g) {
        mloc[g] = wm + g * 16 + l16;
        mg[g]   = row0 + mloc[g];
        mv[g]   = mg[g] < M;
    }
    int si[NAG], ri[NAG];
    #pragma unroll
    for (int g = 0; g < NAG; ++g) { si[g] = 0; ri[g] = 0; }
    if (ASRC == A_EDGE || ASRC == A_ERAW) {
        #pragma unroll
        for (int g = 0; g < NAG; ++g)
            if (mv[g]) { si[g] = edges[2 * mg[g]]; ri[g] = edges[2 * mg[g] + 1]; }
    }

    f32x4 acc[2][NAG];   // [wg][ag]: n = wn+wg*16+quad*4+rg, m = wm+ag*16+l16

    auto zacc = [&] {
        #pragma unroll
        for (int i = 0; i < 2; ++i)
            #pragma unroll
            for (int j = 0; j < NAG; ++j) acc[i][j] = (f32x4)0.f;
    };

    // ---- node aggregate staged once into AG (then read as LDS fragments)
    if (ASRC == A_NODE) {
        const int sr = tid >> 2, sh = tid & 3;
        const bool stg = (tid < BM * 4);
        if (stg) {
            int sm = row0 + sr;
            int jb = 0, je = 0;
            if (sm < M) { jb = rowptr[sm]; je = rowptr[sm + 1]; }
            #pragma unroll
            for (int c2 = 0; c2 < 4; ++c2) {
                float a[8];
                #pragma unroll
                for (int i = 0; i < 8; ++i) a[i] = 0.f;
                const float* base = eEs + c2 * 32 + sh * 8;
                for (int j = jb; j < je; ++j) {
                    const float4* r = (const float4*)(base + (size_t)j * 128);
                    float4 x0 = r[0], x1 = r[1];
                    a[0]+=x0.x; a[1]+=x0.y; a[2]+=x0.z; a[3]+=x0.w;
                    a[4]+=x1.x; a[5]+=x1.y; a[6]+=x1.z; a[7]+=x1.w;
                }
                union { U16 u[8]; int4 v; } pk;
                #pragma unroll
                for (int i = 0; i < 8; ++i) pk.u[i] = f2b(a[i]);
                *(int4*)&AG[sr][c2 * 32 + sh * 8] = pk.v;
            }
        }
        wgb();
    }

    // ---- fragment loaders (register-direct) --------------------------------
    auto ldw = [&](const U16* W, int Kw, int c, short8* wf) {
        wf[0] = *(const short8*)(W + (size_t)wrow0 * Kw + c * 32 + quad * 8);
        wf[1] = *(const short8*)(W + (size_t)wrow1 * Kw + c * 32 + quad * 8);
    };
    auto lda = [&](int c, short8* af) {
        #pragma unroll
        for (int g = 0; g < NAG; ++g) {
            short8 z = {0,0,0,0,0,0,0,0};
            if (ASRC == A_ERAW) {
                if (quad == 0 && mv[g]) {
                    float dx = pos[3*si[g]]   - pos[3*ri[g]];
                    float dy = pos[3*si[g]+1] - pos[3*ri[g]+1];
                    float dz = pos[3*si[g]+2] - pos[3*ri[g]+2];
                    float nm = sqrtf(dx*dx + dy*dy + dz*dz);
                    union { U16 u[8]; short8 v; } pk;
                    pk.u[0]=f2b(dx); pk.u[1]=f2b(dy); pk.u[2]=f2b(dz); pk.u[3]=f2b(nm);
                    pk.u[4]=0; pk.u[5]=0; pk.u[6]=0; pk.u[7]=0;
                    af[g] = pk.v;
                } else af[g] = z;
            } else if (ASRC == A_ENCIN) {
                if (mv[g]) {
                    union { U16 u[8]; short8 v; } pk;
                    #pragma unroll
                    for (int j = 0; j < 8; ++j) {
                        int col = quad * 8 + j;
                        float x = 0.f;
                        if (col < 3)       x = pos[3 * mg[g] + col];
                        else if (col == 3) x = area[mg[g]];
                        else if (col < 12) x = info[col - 4];
                        pk.u[j] = f2b(x);
                    }
                    af[g] = pk.v;
                } else af[g] = z;
            } else if (ASRC == A_BF16) {
                af[g] = mv[g] ? *(const short8*)(Af + (size_t)mg[g] * K1 + c * 32 + quad * 8) : z;
            } else if (ASRC == A_EDGE) {
                const U16* s;
                if (c < 4)      s = Vh  + (size_t)si[g] * 128 + c * 32;
                else if (c < 8) s = Vh  + (size_t)ri[g] * 128 + (c - 4) * 32;
                else            s = Ehp + (size_t)mg[g] * 128 + (c - 8) * 32;
                af[g] = mv[g] ? *(const short8*)(s + quad * 8) : z;
            } else { // A_NODE
                if (c < 4) af[g] = mv[g] ? *(const short8*)(Vh + (size_t)mg[g] * 128 + c * 32 + quad * 8) : z;
                else       af[g] = *(const short8*)&AG[mloc[g]][(c - 4) * 32 + quad * 8];
            }
        }
    };
    auto ldh = [&](int c, short8* af) {
        #pragma unroll
        for (int g = 0; g < NAG; ++g)
            af[g] = *(const short8*)&Hs[mloc[g]][c * 32 + quad * 8];
    };
    auto MF = [&](short8* wf, short8* af) {
        #pragma unroll
        for (int wg = 0; wg < 2; ++wg)
            #pragma unroll
            for (int ag = 0; ag < NAG; ++ag)
                acc[wg][ag] = __builtin_amdgcn_mfma_f32_16x16x32_bf16(
                    wf[wg], af[ag], acc[wg][ag], 0, 0, 0);
    };

    auto hwrite = [&](const float* bias) {
        #pragma unroll
        for (int wg = 0; wg < 2; ++wg) {
            f32x4 bv = *(const f32x4*)&bias[wn + wg*16 + quad*4];
            #pragma unroll
            for (int ag = 0; ag < NAG; ++ag) {
                int m  = mloc[ag];
                int n0 = wn + wg*16 + quad*4;
                union { U16 u[4]; uint2 q; } pk;
                #pragma unroll
                for (int rg = 0; rg < 4; ++rg)
                    pk.u[rg] = f2b(fmaxf(acc[wg][ag][rg] + bv[rg], 0.f));
                *(uint2*)&Hs[m][n0] = pk.q;
            }
        }
    };

    // ---- phase 1: barrier-free, depth-2 register ping-pong
    zacc();
    {
        short8 wf0[2], af0[NAG], wf1[2], af1[NAG];
        ldw(W1, K1, 0, wf0); lda(0, af0);
        if (C1 > 1) { ldw(W1, K1, 1, wf1); lda(1, af1); }
        #pragma unroll
        for (int c = 0; c < C1; ++c) {
            if ((c & 1) == 0) {
                MF(wf0, af0);
                if (c + 2 < C1) { ldw(W1, K1, c + 2, wf0); lda(c + 2, af0); }
            } else {
                MF(wf1, af1);
                if (c + 2 < C1) { ldw(W1, K1, c + 2, wf1); lda(c + 2, af1); }
            }
        }
    }

    // ---- phase 2: A = Hs (published once), W2 register-direct
    hwrite(b1);
    wgb();
    zacc();
    {
        short8 wf0[2], af0[NAG], wf1[2], af1[NAG];
        ldw(W2, 128, 0, wf0); ldh(0, af0);
        ldw(W2, 128, 1, wf1); ldh(1, af1);
        #pragma unroll
        for (int c = 0; c < 4; ++c) {
            if ((c & 1) == 0) {
                MF(wf0, af0);
                if (c + 2 < 4) { ldw(W2, 128, c + 2, wf0); ldh(c + 2, af0); }
            } else {
                MF(wf1, af1);
                if (c + 2 < 4) { ldw(W2, 128, c + 2, wf1); ldh(c + 2, af1); }
            }
        }
    }

    if (EPI == EPI_DEC) {        // decoder: h2 -> Hs, then dot with w3f
        wgb();                   // all waves done reading Hs (phase-2)
        hwrite(b2);
        wgb();
        constexpr int TPR = 512 / BM;      // threads per row
        constexpr int CPT = 128 / TPR;     // cols per thread
        int r = tid / TPR, s8 = tid % TPR;
        int mgd = row0 + r;
        float v = 0.f;
        if (mgd < M) {
            const U16* hr = &Hs[r][s8 * CPT];
            const float* wr = w3f + s8 * CPT;
            #pragma unroll
            for (int j = 0; j < CPT; ++j) v += b2f(hr[j]) * wr[j];
        }
        #pragma unroll
        for (int off = 1; off < TPR; off <<= 1) v += __shfl_xor(v, off);
        if (s8 == 0 && mgd < M) outf[mgd] = v + b3[0];
        return;
    }

    // ---- phase 3
    wgb();                       // all waves done reading Hs (phase-2)
    hwrite(b2);
    wgb();
    zacc();
    {
        short8 wf0[2], af0[NAG], wf1[2], af1[NAG];
        ldw(W3, 128, 0, wf0); ldh(0, af0);
        ldw(W3, 128, 1, wf1); ldh(1, af1);
        #pragma unroll
        for (int c = 0; c < 4; ++c) {
            if ((c & 1) == 0) {
                MF(wf0, af0);
                if (c + 2 < 4) { ldw(W3, 128, c + 2, wf0); ldh(c + 2, af0); }
            } else {
                MF(wf1, af1);
                if (c + 2 < 4) { ldw(W3, 128, c + 2, wf1); ldh(c + 2, af1); }
            }
        }
    }

    // ---- EPI_F: fused LayerNorm epilogue (fp32 stats in LDS, one pass) ------
    if (EPI == EPI_F) {
        #pragma unroll
        for (int wg = 0; wg < 2; ++wg) {
            f32x4 bv = *(const f32x4*)&b3[wn + wg*16 + quad*4];
            #pragma unroll
            for (int ag = 0; ag < NAG; ++ag) {
                int m  = mloc[ag];
                int n0 = wn + wg*16 + quad*4;
                int sw = (m & 7) << 2;          // XOR swizzle vs 512B-stride banks
                #pragma unroll
                for (int rg = 0; rg < 4; ++rg)
                    LNb[m][(n0 + rg) ^ sw] = acc[wg][ag][rg] + bv[rg];
            }
        }
        wgb();
        #pragma unroll
        for (int r = wave; r < BM; r += 8) {
            int mgd = row0 + r;
            int sw = (r & 7) << 2;
            float x0 = LNb[r][lane ^ sw];
            float x1 = LNb[r][(64 + lane) ^ sw];
            float s = x0 + x1, q = x0 * x0 + x1 * x1;
            #pragma unroll
            for (int off = 32; off; off >>= 1) {
                s += __shfl_xor(s, off);
                q += __shfl_xor(q, off);
            }
            float mu  = s * (1.f / 128.f);
            float var = q * (1.f / 128.f) - mu * mu;
            float inv = rsqrtf(var + 1e-5f);
            float y0 = (x0 - mu) * inv * lng[lane]      + lnbp[lane];
            float y1 = (x1 - mu) * inv * lng[64 + lane] + lnbp[64 + lane];
            if (mgd < M) {
                outf[(size_t)mgd * 128 + lane]      = y0;
                outf[(size_t)mgd * 128 + 64 + lane] = y1;
                outh[(size_t)mgd * 128 + lane]      = f2b(y0);
                outh[(size_t)mgd * 128 + 64 + lane] = f2b(y1);
            }
        }
        return;
    }

    // ---- epilogue (residual add; EPI_EDGE also scatters e_emb sender-sorted)
    f32x4 bvs[2];
    #pragma unroll
    for (int wg = 0; wg < 2; ++wg)
        bvs[wg] = *(const f32x4*)&b3[wn + wg*16 + quad*4];
    #pragma unroll
    for (int ag = 0; ag < NAG; ++ag) {
        if (!mv[ag]) continue;
        int mgd = mg[ag];
        int sp = 0;
        if (EPI == EPI_EDGE) sp = spos[mgd];
        #pragma unroll
        for (int wg = 0; wg < 2; ++wg) {
            int n0 = wn + wg*16 + quad*4;
            f32x4 v;
            #pragma unroll
            for (int rg = 0; rg < 4; ++rg) v[rg] = acc[wg][ag][rg] + bvs[wg][rg];
            size_t o = (size_t)mgd * 128 + n0;
            f32x4 c = *(f32x4*)&outf[o];
            c += v;
            *(f32x4*)&outf[o] = c;
            union { U16 u[4]; uint2 q; } pk;
            #pragma unroll
            for (int rg = 0; rg < 4; ++rg) pk.u[rg] = f2b(c[rg]);
            *(uint2*)&outh[o] = pk.q;
            if (EPI == EPI_EDGE)
                *(f32x4*)&eEs[(size_t)sp * 128 + n0] = v;   // sorted e_emb
        }
    }
}

extern "C" void kernel_launch(void* const* d_in, const int* in_sizes, int n_in,
                              void* d_out, int out_size, void* d_ws, size_t ws_size,
                              hipStream_t stream)
{
    (void)in_sizes; (void)n_in; (void)out_size; (void)ws_size;

    const float* pos   = (const float*)d_in[0];
    const float* area  = (const float*)d_in[1];
    const float* info  = (const float*)d_in[2];
    const int*   edges = (const int*)d_in[3];
    const float* fv_w1 = (const float*)d_in[4];
    const float* fv_b1 = (const float*)d_in[5];
    const float* fv_w2 = (const float*)d_in[6];
    const float* fv_b2 = (const float*)d_in[7];
    const float* fv_w3 = (const float*)d_in[8];
    const float* fv_b3 = (const float*)d_in[9];
    const float* fv_g  = (const float*)d_in[10];
    const float* fv_bt = (const float*)d_in[11];
    const float* fe_w1 = (const float*)d_in[12];
    const float* fe_b1 = (const float*)d_in[13];
    const float* fe_w2 = (const float*)d_in[14];
    const float* fe_b2 = (const float*)d_in[15];
    const float* fe_w3 = (const float*)d_in[16];
    const float* fe_b3 = (const float*)d_in[17];
    const float* fe_g  = (const float*)d_in[18];
    const float* fe_bt = (const float*)d_in[19];
    const float* ge_w1 = (const float*)d_in[20];
    const float* ge_b1 = (const float*)d_in[21];
    const float* ge_w2 = (const float*)d_in[22];
    const float* ge_b2 = (const float*)d_in[23];
    const float* ge_w3 = (const float*)d_in[24];
    const float* ge_b3 = (const float*)d_in[25];
    const float* gn_w1 = (const float*)d_in[26];
    const float* gn_b1 = (const float*)d_in[27];
    const float* gn_w2 = (const float*)d_in[28];
    const float* gn_b2 = (const float*)d_in[29];
    const float* gn_w3 = (const float*)d_in[30];
    const float* gn_b3 = (const float*)d_in[31];
    const float* de_w1 = (const float*)d_in[32];
    const float* de_b1 = (const float*)d_in[33];
    const float* de_w2 = (const float*)d_in[34];
    const float* de_b2 = (const float*)d_in[35];
    const float* de_w3 = (const float*)d_in[36];
    const float* de_b3 = (const float*)d_in[37];

    // workspace layout (~64 MB)
    char* p = (char*)d_ws;
    float* Vf   = (float*)p;  p += (size_t)N_NODE * 128 * 4;
    float* Ef   = (float*)p;  p += (size_t)N_EDGE * 128 * 4;
    float* eEs  = (float*)p;  p += (size_t)N_EDGE * 128 * 4;
    U16*  Vh    = (U16*)p;    p += (size_t)N_NODE * 128 * 2;
    U16*  Eh    = (U16*)p;    p += (size_t)N_EDGE * 128 * 2;
    U16*  Wt    = (U16*)p;    p += (size_t)WT_TOTAL * 2;
    int*  rowptr = (int*)p;   p += (size_t)(N_NODE + 4) * 4;
    int*  cursor = (int*)p;   p += (size_t)N_NODE * 4;
    int*  cnt    = (int*)p;   p += (size_t)N_NODE * 4;
    int*  spos   = (int*)p;   p += (size_t)N_EDGE * 4;

    const int gbE  = (N_EDGE + 63) / 64;    // 625 (BM=64)
    const int gbN  = (N_NODE + 31) / 32;    // 313 (BM=32)

    // ---- prep: weights, CSR
    wprep<<<566, 256, 0, stream>>>(fv_w1, fv_w2, fv_w3, fe_w1, fe_w2, fe_w3,
                                   ge_w1, ge_w2, ge_w3, gn_w1, gn_w2, gn_w3,
                                   de_w1, de_w2, Wt);
    hipMemsetAsync(cnt, 0, (size_t)N_NODE * 4, stream);
    csr_hist<<<(N_EDGE + 255) / 256, 256, 0, stream>>>(edges, cnt, N_EDGE);
    csr_scan<<<1, 256, 0, stream>>>(cnt, rowptr, cursor, N_NODE);
    csr_scatter<<<(N_EDGE + 255) / 256, 256, 0, stream>>>(edges, cursor, spos, N_EDGE);

    // ---- edge encoder (eraw fused, LN fused) -> Ef + Eh
    mlp3<A_ERAW, EPI_F, 32, 64><<<gbE, 512, 0, stream>>>(
        nullptr, Wt + OFF_FE1, fe_b1, Wt + OFF_FE2, fe_b2, Wt + OFF_FE3, fe_b3,
        Eh, Ef, edges, nullptr, nullptr, nullptr, nullptr, nullptr,
        pos, nullptr, nullptr, nullptr, fe_g, fe_bt, N_EDGE);

    // ---- node encoder (encin fused, LN fused) -> Vf + Vh
    mlp3<A_ENCIN, EPI_F, 32, 32><<<gbN, 512, 0, stream>>>(
        nullptr, Wt + OFF_FV1, fv_b1, Wt + OFF_FV2, fv_b2, Wt + OFF_FV3, fv_b3,
        Vh, Vf, nullptr, nullptr, nullptr, nullptr, nullptr, nullptr,
        pos, area, info, nullptr, fv_g, fv_bt, N_NODE);

    // ---- 15 GNN layers
    for (int l = 0; l < N_LAYER; ++l) {
        mlp3<A_EDGE, EPI_EDGE, 384, 64><<<gbE, 512, 0, stream>>>(
            nullptr,
            Wt + OFF_GE1 + (size_t)l * 49152, ge_b1 + (size_t)l * 128,
            Wt + OFF_GE2 + (size_t)l * 16384, ge_b2 + (size_t)l * 128,
            Wt + OFF_GE3 + (size_t)l * 16384, ge_b3 + (size_t)l * 128,
            Eh, Ef, edges, nullptr, spos, eEs, Vh, Eh,
            nullptr, nullptr, nullptr, nullptr, nullptr, nullptr, N_EDGE);
        mlp3<A_NODE, EPI_NODE, 256, 32><<<gbN, 512, 0, stream>>>(
            nullptr,
            Wt + OFF_GN1 + (size_t)l * 32768, gn_b1 + (size_t)l * 128,
            Wt + OFF_GN2 + (size_t)l * 16384, gn_b2 + (size_t)l * 128,
            Wt + OFF_GN3 + (size_t)l * 16384, gn_b3 + (size_t)l * 128,
            Vh, Vf, nullptr, rowptr, spos, eEs, Vh, nullptr,
            nullptr, nullptr, nullptr, nullptr, nullptr, nullptr, N_NODE);
    }

    // ---- decoder
    mlp3<A_BF16, EPI_DEC, 128, 32><<<gbN, 512, 0, stream>>>(
        Vh, Wt + OFF_DE1, de_b1, Wt + OFF_DE2, de_b2, nullptr, de_b3,
        nullptr, (float*)d_out, nullptr, nullptr, nullptr, nullptr, nullptr, nullptr,
        nullptr, nullptr, nullptr, de_w3, nullptr, nullptr, N_NODE);
}

// Round 5
// 1291.225 us; speedup vs baseline: 1.2364x; 1.2364x over previous
//
#include <hip/hip_runtime.h>

#define N_NODE 10000
#define N_EDGE 40000
#define N_LAYER 15

typedef unsigned short U16;
typedef __attribute__((ext_vector_type(8))) short short8;
typedef __attribute__((ext_vector_type(4))) float f32x4;

enum { A_BF16 = 0, A_EDGE, A_NODE, A_ENCIN, A_ERAW };
enum { EPI_F = 0, EPI_EDGE, EPI_NODE, EPI_DEC };

// Wt layout offsets (bf16 elements), [n=128][Kpad] per matrix
#define OFF_FV1 0
#define OFF_FV2 4096
#define OFF_FV3 20480
#define OFF_FE1 36864
#define OFF_FE2 40960
#define OFF_FE3 57344
#define OFF_GE1 73728     /* stride 49152 (Kpad=384) */
#define OFF_GE2 811008    /* stride 16384 */
#define OFF_GE3 1056768
#define OFF_GN1 1302528   /* stride 32768 (Kpad=256) */
#define OFF_GN2 1794048
#define OFF_GN3 2039808
#define OFF_DE1 2285568
#define OFF_DE2 2301952
#define WT_TOTAL 2318336

static __device__ __forceinline__ U16 f2b(float f) {
    union { float f; unsigned u; } x; x.f = f;
    unsigned u = x.u;
    return (U16)((u + 0x7fffu + ((u >> 16) & 1u)) >> 16);
}
static __device__ __forceinline__ float b2f(U16 u) {
    union { unsigned u; float f; } x; x.u = ((unsigned)u) << 16;
    return x.f;
}

// workgroup barrier draining ONLY lgkmcnt; global loads in flight survive it.
static __device__ __forceinline__ void wgb() {
    __asm__ __volatile__("s_waitcnt lgkmcnt(0)\n\ts_barrier" ::: "memory");
}

// ---------------- weight transpose+cast: W[K][128] f32 -> Wt[n][Kpad] bf16 ----
__global__ __launch_bounds__(256)
void wprep(const float* fv1, const float* fv2, const float* fv3,
           const float* fe1, const float* fe2, const float* fe3,
           const float* ge1, const float* ge2, const float* ge3,
           const float* gn1, const float* gn2, const float* gn3,
           const float* de1, const float* de2, U16* Wt)
{
    int b = blockIdx.x;
    const float* src; U16* dst; int K, Kpad, k0;
    if      (b < 1)   { src = fv1; K = 12;  Kpad = 32;  dst = Wt + OFF_FV1; k0 = b * 32; }
    else if (b < 5)   { src = fv2; K = 128; Kpad = 128; dst = Wt + OFF_FV2; k0 = (b-1)*32; }
    else if (b < 9)   { src = fv3; K = 128; Kpad = 128; dst = Wt + OFF_FV3; k0 = (b-5)*32; }
    else if (b < 10)  { src = fe1; K = 4;   Kpad = 32;  dst = Wt + OFF_FE1; k0 = (b-9)*32; }
    else if (b < 14)  { src = fe2; K = 128; Kpad = 128; dst = Wt + OFF_FE2; k0 = (b-10)*32; }
    else if (b < 18)  { src = fe3; K = 128; Kpad = 128; dst = Wt + OFF_FE3; k0 = (b-14)*32; }
    else if (b < 198) { int r = b-18,  mi = r/12, s = r%12; src = ge1 + (size_t)mi*384*128; K = 384; Kpad = 384; dst = Wt + OFF_GE1 + (size_t)mi*49152; k0 = s*32; }
    else if (b < 258) { int r = b-198, mi = r/4,  s = r%4;  src = ge2 + (size_t)mi*16384;   K = 128; Kpad = 128; dst = Wt + OFF_GE2 + (size_t)mi*16384; k0 = s*32; }
    else if (b < 318) { int r = b-258, mi = r/4,  s = r%4;  src = ge3 + (size_t)mi*16384;   K = 128; Kpad = 128; dst = Wt + OFF_GE3 + (size_t)mi*16384; k0 = s*32; }
    else if (b < 438) { int r = b-318, mi = r/8,  s = r%8;  src = gn1 + (size_t)mi*32768;   K = 256; Kpad = 256; dst = Wt + OFF_GN1 + (size_t)mi*32768; k0 = s*32; }
    else if (b < 498) { int r = b-438, mi = r/4,  s = r%4;  src = gn2 + (size_t)mi*16384;   K = 128; Kpad = 128; dst = Wt + OFF_GN2 + (size_t)mi*16384; k0 = s*32; }
    else if (b < 558) { int r = b-498, mi = r/4,  s = r%4;  src = gn3 + (size_t)mi*16384;   K = 128; Kpad = 128; dst = Wt + OFF_GN3 + (size_t)mi*16384; k0 = s*32; }
    else if (b < 562) { src = de1; K = 128; Kpad = 128; dst = Wt + OFF_DE1; k0 = (b-558)*32; }
    else              { src = de2; K = 128; Kpad = 128; dst = Wt + OFF_DE2; k0 = (b-562)*32; }

    __shared__ float T[32][129];
    #pragma unroll
    for (int i = 0; i < 16; ++i) {
        int l = threadIdx.x + i * 256;
        int kk = l >> 7, n = l & 127;
        int kg = k0 + kk;
        T[kk][n] = (kg < K) ? src[(size_t)kg * 128 + n] : 0.f;
    }
    __syncthreads();
    int n = threadIdx.x >> 1, h = threadIdx.x & 1;
    union { U16 u[16]; int4 v[2]; } o;
    #pragma unroll
    for (int j = 0; j < 16; ++j) o.u[j] = f2b(T[h * 16 + j][n]);
    int4* d = (int4*)(dst + (size_t)n * Kpad + k0 + h * 16);
    d[0] = o.v[0]; d[1] = o.v[1];
}

// ---------------- CSR build (sender-sorted positions) ------------------------
__global__ __launch_bounds__(256)
void csr_hist(const int* __restrict__ edges, int* __restrict__ cnt, int Eg)
{
    int e = blockIdx.x * 256 + threadIdx.x;
    if (e < Eg) atomicAdd(&cnt[edges[2 * e]], 1);
}

__global__ __launch_bounds__(256)
void csr_scan(const int* __restrict__ cnt, int* __restrict__ rowptr,
              int* __restrict__ cursor, int n)
{
    __shared__ int ps[256];
    int t = threadIdx.x, base = t * 40;
    int s = 0;
    for (int j = 0; j < 40; ++j) if (base + j < n) s += cnt[base + j];
    ps[t] = s; __syncthreads();
    for (int off = 1; off < 256; off <<= 1) {
        int v = (t >= off) ? ps[t - off] : 0;
        __syncthreads();
        ps[t] += v;
        __syncthreads();
    }
    int run = ps[t] - s;   // exclusive prefix
    for (int j = 0; j < 40; ++j) {
        if (base + j < n) {
            rowptr[base + j] = run;
            cursor[base + j] = run;
            run += cnt[base + j];
        }
    }
    if (t == 255) rowptr[n] = ps[255];
}

// spos[e] = position of edge e in the sender-sorted order
__global__ __launch_bounds__(256)
void csr_scatter(const int* __restrict__ edges, int* __restrict__ cursor,
                 int* __restrict__ spos, int Eg)
{
    int e = blockIdx.x * 256 + threadIdx.x;
    if (e < Eg) spos[e] = atomicAdd(&cursor[edges[2 * e]], 1);
}

// ---------------- Yv = Vh @ [W1s | W1r] : dense per-layer pre-GEMM -----------
// Yv[m][n]     = sum_k Vh[m][k] * WtGE1[n][k]        (n < 128, sender part)
// Yv[m][128+n] = sum_k Vh[m][k] * WtGE1[n][128+k]    (receiver part)
// fp32 output, no bias/relu (added in the edge kernel's h1 epilogue).
__global__ __launch_bounds__(512, 4)
void yv_kernel(const U16* __restrict__ Vh, const U16* __restrict__ Wg,
               float* __restrict__ Yv, int M)
{
    __shared__ U16 Vs[32][132];
    const int tid = threadIdx.x;
    const int row0 = blockIdx.x * 32;
    {
        int r = tid >> 4, cl = (tid & 15) * 8;
        int gm = row0 + r;
        int4 v = (gm < M) ? *(const int4*)(Vh + (size_t)gm * 128 + cl)
                          : make_int4(0, 0, 0, 0);
        *(int4*)&Vs[r][cl] = v;
    }
    wgb();
    const int wave = tid >> 6, lane = tid & 63;
    const int quad = lane >> 4, l16 = lane & 15;
    const int half = wave >> 2;              // 0: out cols 0-127; 1: 128-255
    const int wr0  = wave * 32 - half * 128; // Wt row base for this wave
    const int koff = half * 128;
    f32x4 acc[2][2];
    #pragma unroll
    for (int i = 0; i < 2; ++i)
        #pragma unroll
        for (int j = 0; j < 2; ++j) acc[i][j] = (f32x4)0.f;
    #pragma unroll
    for (int c = 0; c < 4; ++c) {
        short8 wf0 = *(const short8*)(Wg + (size_t)(wr0 + l16)      * 384 + koff + c * 32 + quad * 8);
        short8 wf1 = *(const short8*)(Wg + (size_t)(wr0 + 16 + l16) * 384 + koff + c * 32 + quad * 8);
        short8 a0  = *(const short8*)&Vs[l16][c * 32 + quad * 8];
        short8 a1  = *(const short8*)&Vs[16 + l16][c * 32 + quad * 8];
        acc[0][0] = __builtin_amdgcn_mfma_f32_16x16x32_bf16(wf0, a0, acc[0][0], 0, 0, 0);
        acc[0][1] = __builtin_amdgcn_mfma_f32_16x16x32_bf16(wf0, a1, acc[0][1], 0, 0, 0);
        acc[1][0] = __builtin_amdgcn_mfma_f32_16x16x32_bf16(wf1, a0, acc[1][0], 0, 0, 0);
        acc[1][1] = __builtin_amdgcn_mfma_f32_16x16x32_bf16(wf1, a1, acc[1][1], 0, 0, 0);
    }
    #pragma unroll
    for (int wg = 0; wg < 2; ++wg)
        #pragma unroll
        for (int ag = 0; ag < 2; ++ag) {
            int m = row0 + ag * 16 + l16;
            if (m < M) {
                int n0 = wave * 32 + wg * 16 + quad * 4;
                *(f32x4*)&Yv[(size_t)m * 256 + n0] = acc[wg][ag];
            }
        }
}

// ---------------- fused 3-layer MLP (MFMA, W-as-A, pipelined K-loop) ---------
// R1 chassis (LDS staging, depth-2 prefetch, lgkmcnt-only barriers; measured
// 1037us total) with the edge-gather poison removed: A_EDGE phase-1 is now a
// CONTIGUOUS K=128 GEMM over edge-ordered Eh (W1e slice, k-offset 256 of the
// [n][384] GE1 panel); the sender/receiver contributions come from the dense
// per-layer Yv GEMM, gathered per-lane ONCE (issued after the phase-1 loop,
// consumed in the h1 epilogue -> latency paid once per block, not per chunk).
// Extras kept from R2/R3 (mechanism-safe): As/Hs LDS overlay, LN-fused EPI_F,
// merged phase-transition barrier. Node kernel = exact R1 path.
template<int ASRC, int EPI, int K1, int KW1, int BM>
__global__ __launch_bounds__(512, 4)
void mlp3(const U16* __restrict__ Af,
          const U16* __restrict__ W1, const float* __restrict__ b1,
          const U16* __restrict__ W2, const float* __restrict__ b2,
          const U16* __restrict__ W3, const float* __restrict__ b3,
          U16* __restrict__ outh, float* __restrict__ outf,
          const int* __restrict__ edges, const int* __restrict__ rowptr,
          const int* __restrict__ spos, float* __restrict__ eEs,
          const U16* __restrict__ Vh, const U16* __restrict__ Ehp,
          const float* __restrict__ pos, const float* __restrict__ area,
          const float* __restrict__ info, const float* __restrict__ w3f,
          const float* __restrict__ lng, const float* __restrict__ lnbp,
          const float* __restrict__ yvp,
          int M)
{
    constexpr int NAG = BM / 32;              // A fragments per wave (m-dir)
    constexpr int C1  = K1 / 32;
    constexpr int BSB = 2 * 128 * 40 * 2;     // Bs bytes (20480)
    constexpr int ASB = 2 * BM * 40 * 2;      // As dbuf bytes
    constexpr int HSB = BM * 132 * 2;         // Hs bytes
    constexpr int PLB = (ASB > HSB) ? ASB : HSB;
    constexpr int LNBY = (EPI == EPI_F) ? BM * 128 * 4 : 0;
    constexpr int SMB = (BSB + PLB > LNBY) ? (BSB + PLB) : LNBY;
    __shared__ __align__(16) char smem[SMB];
    auto Bs  = (U16 (*)[128][40])smem;        // [2][128][40] W tiles
    auto As  = (U16 (*)[BM][40])(smem + BSB); // [2][BM][40]  phase-1 A tiles
    auto Hs  = (U16 (*)[132])(smem + BSB);    // [BM][132]    overlays As
    auto LNb = (float (*)[128])smem;          // [BM][128]    EPI_F only

    const int tid  = threadIdx.x;
    const int row0 = blockIdx.x * BM;
    const int wave = tid >> 6, lane = tid & 63;
    const int quad = lane >> 4, l16 = lane & 15;
    const int wm = (wave >> 2) * (16 * NAG);   // wave m-offset
    const int wn = (wave & 3) * 32;            // wave n-offset (0/32/64/96)
    const int sr = tid >> 2, sh = tid & 3;     // A staging: row, 8-col chunk
    const int br = tid >> 2, bh = tid & 3;     // W staging: row, 8-col chunk
    const int sm = row0 + sr;
    const bool stager = (tid < BM * 4);        // threads that stage A
    const bool valid  = stager && (sm < M);

    // stager-side edge endpoints (encoder eraw only)
    int si = 0, ri = 0, jbeg = 0, jend = 0;
    if (ASRC == A_ERAW && valid) {
        si = edges[2 * sm]; ri = edges[2 * sm + 1];
    }
    if (ASRC == A_NODE && valid) { jbeg = rowptr[sm]; jend = rowptr[sm + 1]; }

    // per-lane edge endpoints for the Yv gather (A_EDGE only)
    int egS[NAG], egR[NAG];
    if (ASRC == A_EDGE) {
        #pragma unroll
        for (int g = 0; g < NAG; ++g) {
            int mr = row0 + wm + g * 16 + l16;
            egS[g] = (mr < M) ? edges[2 * mr]     : 0;
            egR[g] = (mr < M) ? edges[2 * mr + 1] : 0;
        }
    }

    f32x4 acc[2][NAG];   // [wg][ag]: n = wn+wg*16+quad*4+rg, m = wm+ag*16+l16

    auto zacc = [&] {
        #pragma unroll
        for (int i = 0; i < 2; ++i)
            #pragma unroll
            for (int j = 0; j < NAG; ++j) acc[i][j] = (f32x4)0.f;
    };

    auto ldA = [&](int c) -> int4 {
        if (ASRC == A_ENCIN || ASRC == A_ERAW) {
            union { U16 u[8]; int4 v; } pk;
            #pragma unroll
            for (int j = 0; j < 8; ++j) pk.u[j] = 0;
            if (valid) {
                if (ASRC == A_ENCIN) {
                    #pragma unroll
                    for (int j = 0; j < 8; ++j) {
                        int col = sh * 8 + j;
                        float x = 0.f;
                        if (col < 3)       x = pos[3 * sm + col];
                        else if (col == 3) x = area[sm];
                        else if (col < 12) x = info[col - 4];
                        pk.u[j] = f2b(x);
                    }
                } else if (sh == 0) {
                    float dx = pos[3*si]   - pos[3*ri];
                    float dy = pos[3*si+1] - pos[3*ri+1];
                    float dz = pos[3*si+2] - pos[3*ri+2];
                    float nm = sqrtf(dx*dx + dy*dy + dz*dz);
                    pk.u[0] = f2b(dx); pk.u[1] = f2b(dy);
                    pk.u[2] = f2b(dz); pk.u[3] = f2b(nm);
                }
            }
            return pk.v;
        } else if (ASRC == A_NODE && c >= 4) {
            // segmented sum over sender-sorted e_emb rows (fp32) -> bf16
            float a[8];
            #pragma unroll
            for (int i = 0; i < 8; ++i) a[i] = 0.f;
            if (valid) {
                const float* base = eEs + (c - 4) * 32 + sh * 8;
                for (int j = jbeg; j < jend; ++j) {
                    const float4* r = (const float4*)(base + (size_t)j * 128);
                    float4 x0 = r[0], x1 = r[1];
                    a[0]+=x0.x; a[1]+=x0.y; a[2]+=x0.z; a[3]+=x0.w;
                    a[4]+=x1.x; a[5]+=x1.y; a[6]+=x1.z; a[7]+=x1.w;
                }
            }
            union { U16 u[8]; int4 v; } pk;
            #pragma unroll
            for (int i = 0; i < 8; ++i) pk.u[i] = f2b(a[i]);
            return pk.v;
        } else {
            const U16* s;
            if (ASRC == A_BF16)      s = Af  + (size_t)sm * K1 + c * 32;
            else if (ASRC == A_EDGE) s = Ehp + (size_t)sm * 128 + c * 32;  // contiguous!
            else                     s = Vh  + (size_t)sm * 128 + c * 32;  // A_NODE c<4
            return valid ? *(const int4*)(s + sh * 8) : make_int4(0,0,0,0);
        }
    };

    auto ldW = [&](const U16* W, int Kw, int c) -> int4 {
        const U16* s = W + (size_t)br * Kw + c * 32 + bh * 8;
        return *(const int4*)s;
    };

    auto wrA = [&](int b, int4 v) { if (stager) *(int4*)&As[b][sr][sh * 8] = v; };
    auto wrW = [&](int b, int4 w) { *(int4*)&Bs[b][br][bh * 8] = w; };

    auto mfA = [&](int b) {   // A from As[b], W from Bs[b]
        short8 wf[2], af[NAG];
        #pragma unroll
        for (int g = 0; g < 2; ++g)
            wf[g] = *(const short8*)&Bs[b][wn + g*16 + l16][quad * 8];
        #pragma unroll
        for (int g = 0; g < NAG; ++g)
            af[g] = *(const short8*)&As[b][wm + g*16 + l16][quad * 8];
        #pragma unroll
        for (int wg = 0; wg < 2; ++wg)
            #pragma unroll
            for (int ag = 0; ag < NAG; ++ag)
                acc[wg][ag] = __builtin_amdgcn_mfma_f32_16x16x32_bf16(
                    wf[wg], af[ag], acc[wg][ag], 0, 0, 0);
    };

    auto mfH = [&](int c, int b) {   // A from Hs slice c, W from Bs[b]
        short8 wf[2], af[NAG];
        #pragma unroll
        for (int g = 0; g < 2; ++g)
            wf[g] = *(const short8*)&Bs[b][wn + g*16 + l16][quad * 8];
        #pragma unroll
        for (int g = 0; g < NAG; ++g)
            af[g] = *(const short8*)&Hs[wm + g*16 + l16][c * 32 + quad * 8];
        #pragma unroll
        for (int wg = 0; wg < 2; ++wg)
            #pragma unroll
            for (int ag = 0; ag < NAG; ++ag)
                acc[wg][ag] = __builtin_amdgcn_mfma_f32_16x16x32_bf16(
                    wf[wg], af[ag], acc[wg][ag], 0, 0, 0);
    };

    auto hwrite = [&](const float* bias) {
        #pragma unroll
        for (int wg = 0; wg < 2; ++wg) {
            f32x4 bv = *(const f32x4*)&bias[wn + wg*16 + quad*4];
            #pragma unroll
            for (int ag = 0; ag < NAG; ++ag) {
                int m  = wm + ag*16 + l16;
                int n0 = wn + wg*16 + quad*4;
                union { U16 u[4]; uint2 q; } pk;
                #pragma unroll
                for (int rg = 0; rg < 4; ++rg)
                    pk.u[rg] = f2b(fmaxf(acc[wg][ag][rg] + bv[rg], 0.f));
                *(uint2*)&Hs[m][n0] = pk.q;
            }
        }
    };

    int4 ra0, ra1, rw0, rw1;

    // ---- phase 1: depth-2 register-prefetch pipeline (R1 scheme)
    zacc();
    ra0 = ldA(0); rw0 = ldW(W1, KW1, 0);
    if (C1 > 1) { ra1 = ldA(1); rw1 = ldW(W1, KW1, 1); }
    wrA(0, ra0); wrW(0, rw0);
    wgb();
    #pragma unroll
    for (int c = 0; c < C1; ++c) {
        if (c + 2 < C1) {                      // prefetch chunk c+2 (parity c&1)
            if ((c & 1) == 0) { ra0 = ldA(c + 2); rw0 = ldW(W1, KW1, c + 2); }
            else              { ra1 = ldA(c + 2); rw1 = ldW(W1, KW1, c + 2); }
        }
        if (c + 1 < C1) {                      // commit chunk c+1 to LDS
            if (((c + 1) & 1) == 0) { wrA(0, ra0); wrW(0, rw0); }
            else                    { wrA(1, ra1); wrW(1, rw1); }
        }
        mfA(c & 1);
        wgb();
    }

    // ---- Yv gather (A_EDGE): one shot, consumed immediately in h1 epilogue
    f32x4 g1[2][NAG], g2[2][NAG];
    if (ASRC == A_EDGE) {
        #pragma unroll
        for (int wg = 0; wg < 2; ++wg)
            #pragma unroll
            for (int ag = 0; ag < NAG; ++ag) {
                int mr = row0 + wm + ag * 16 + l16;
                int n0 = wn + wg * 16 + quad * 4;
                g1[wg][ag] = (mr < M) ? *(const f32x4*)&yvp[(size_t)egS[ag] * 256 + n0]       : (f32x4)0.f;
                g2[wg][ag] = (mr < M) ? *(const f32x4*)&yvp[(size_t)egR[ag] * 256 + 128 + n0] : (f32x4)0.f;
            }
    }

    // ---- phase 2 transition (single barrier; loop above ended with wgb)
    rw0 = ldW(W2, 128, 0); rw1 = ldW(W2, 128, 1);
    if (ASRC == A_EDGE) {
        #pragma unroll
        for (int wg = 0; wg < 2; ++wg) {
            f32x4 bv = *(const f32x4*)&b1[wn + wg*16 + quad*4];
            #pragma unroll
            for (int ag = 0; ag < NAG; ++ag) {
                int m  = wm + ag*16 + l16;
                int n0 = wn + wg*16 + quad*4;
                union { U16 u[4]; uint2 q; } pk;
                #pragma unroll
                for (int rg = 0; rg < 4; ++rg) {
                    float v = acc[wg][ag][rg] + bv[rg]
                            + g1[wg][ag][rg] + g2[wg][ag][rg];
                    pk.u[rg] = f2b(fmaxf(v, 0.f));
                }
                *(uint2*)&Hs[m][n0] = pk.q;
            }
        }
    } else {
        hwrite(b1);
    }
    zacc();
    wrW(0, rw0);
    wgb();
    #pragma unroll
    for (int c = 0; c < 4; ++c) {
        if (c + 2 < 4) {
            if ((c & 1) == 0) rw0 = ldW(W2, 128, c + 2);
            else              rw1 = ldW(W2, 128, c + 2);
        }
        if (c + 1 < 4) {
            if (((c + 1) & 1) == 0) wrW(0, rw0);
            else                    wrW(1, rw1);
        }
        mfH(c, c & 1);
        wgb();
    }

    if (EPI == EPI_DEC) {        // decoder: h2 -> Hs, then dot with w3f
        hwrite(b2);
        wgb();
        constexpr int TPR = 512 / BM;      // threads per row
        constexpr int CPT = 128 / TPR;     // cols per thread
        int r = tid / TPR, s8 = tid % TPR;
        int mgd = row0 + r;
        float v = 0.f;
        if (mgd < M) {
            const U16* hr = &Hs[r][s8 * CPT];
            const float* wr = w3f + s8 * CPT;
            #pragma unroll
            for (int j = 0; j < CPT; ++j) v += b2f(hr[j]) * wr[j];
        }
        #pragma unroll
        for (int off = 1; off < TPR; off <<= 1) v += __shfl_xor(v, off);
        if (s8 == 0 && mgd < M) outf[mgd] = v + b3[0];
        return;
    }

    // ---- phase 3 transition (single barrier)
    rw0 = ldW(W3, 128, 0); rw1 = ldW(W3, 128, 1);
    hwrite(b2);
    zacc();
    wrW(0, rw0);
    wgb();
    #pragma unroll
    for (int c = 0; c < 4; ++c) {
        if (c + 2 < 4) {
            if ((c & 1) == 0) rw0 = ldW(W3, 128, c + 2);
            else              rw1 = ldW(W3, 128, c + 2);
        }
        if (c + 1 < 4) {
            if (((c + 1) & 1) == 0) wrW(0, rw0);
            else                    wrW(1, rw1);
        }
        mfH(c, c & 1);
        wgb();
    }

    // ---- EPI_F: fused LayerNorm epilogue (fp32 stats in LDS, one pass) ------
    if (EPI == EPI_F) {
        #pragma unroll
        for (int wg = 0; wg < 2; ++wg) {
            f32x4 bv = *(const f32x4*)&b3[wn + wg*16 + quad*4];
            #pragma unroll
            for (int ag = 0; ag < NAG; ++ag) {
                int m  = wm + ag*16 + l16;
                int n0 = wn + wg*16 + quad*4;
                int sw = (m & 7) << 2;          // XOR swizzle vs 512B-stride banks
                #pragma unroll
                for (int rg = 0; rg < 4; ++rg)
                    LNb[m][(n0 + rg) ^ sw] = acc[wg][ag][rg] + bv[rg];
            }
        }
        wgb();
        for (int r = wave; r < BM; r += 8) {
            int mgd = row0 + r;
            int sw = (r & 7) << 2;
            float x0 = LNb[r][lane ^ sw];
            float x1 = LNb[r][(64 + lane) ^ sw];
            float s = x0 + x1, q = x0 * x0 + x1 * x1;
            #pragma unroll
            for (int off = 32; off; off >>= 1) {
                s += __shfl_xor(s, off);
                q += __shfl_xor(q, off);
            }
            float mu  = s * (1.f / 128.f);
            float var = q * (1.f / 128.f) - mu * mu;
            float inv = rsqrtf(var + 1e-5f);
            float y0 = (x0 - mu) * inv * lng[lane]      + lnbp[lane];
            float y1 = (x1 - mu) * inv * lng[64 + lane] + lnbp[64 + lane];
            if (mgd < M) {
                outf[(size_t)mgd * 128 + lane]      = y0;
                outf[(size_t)mgd * 128 + 64 + lane] = y1;
                outh[(size_t)mgd * 128 + lane]      = f2b(y0);
                outh[(size_t)mgd * 128 + 64 + lane] = f2b(y1);
            }
        }
        return;
    }

    // ---- epilogue (residual add; EPI_EDGE also scatters e_emb sender-sorted)
    f32x4 bvs[2];
    #pragma unroll
    for (int wg = 0; wg < 2; ++wg)
        bvs[wg] = *(const f32x4*)&b3[wn + wg*16 + quad*4];
    #pragma unroll
    for (int ag = 0; ag < NAG; ++ag) {
        int mgd = row0 + wm + ag*16 + l16;
        if (mgd >= M) continue;
        int sp = 0;
        if (EPI == EPI_EDGE) sp = spos[mgd];
        #pragma unroll
        for (int wg = 0; wg < 2; ++wg) {
            int n0 = wn + wg*16 + quad*4;
            f32x4 v;
            #pragma unroll
            for (int rg = 0; rg < 4; ++rg) v[rg] = acc[wg][ag][rg] + bvs[wg][rg];
            size_t o = (size_t)mgd * 128 + n0;
            f32x4 c = *(f32x4*)&outf[o];
            c += v;
            *(f32x4*)&outf[o] = c;
            union { U16 u[4]; uint2 q; } pk;
            #pragma unroll
            for (int rg = 0; rg < 4; ++rg) pk.u[rg] = f2b(c[rg]);
            *(uint2*)&outh[o] = pk.q;
            if (EPI == EPI_EDGE)
                *(f32x4*)&eEs[(size_t)sp * 128 + n0] = v;   // sorted e_emb
        }
    }
}

extern "C" void kernel_launch(void* const* d_in, const int* in_sizes, int n_in,
                              void* d_out, int out_size, void* d_ws, size_t ws_size,
                              hipStream_t stream)
{
    (void)in_sizes; (void)n_in; (void)out_size; (void)ws_size;

    const float* pos   = (const float*)d_in[0];
    const float* area  = (const float*)d_in[1];
    const float* info  = (const float*)d_in[2];
    const int*   edges = (const int*)d_in[3];
    const float* fv_w1 = (const float*)d_in[4];
    const float* fv_b1 = (const float*)d_in[5];
    const float* fv_w2 = (const float*)d_in[6];
    const float* fv_b2 = (const float*)d_in[7];
    const float* fv_w3 = (const float*)d_in[8];
    const float* fv_b3 = (const float*)d_in[9];
    const float* fv_g  = (const float*)d_in[10];
    const float* fv_bt = (const float*)d_in[11];
    const float* fe_w1 = (const float*)d_in[12];
    const float* fe_b1 = (const float*)d_in[13];
    const float* fe_w2 = (const float*)d_in[14];
    const float* fe_b2 = (const float*)d_in[15];
    const float* fe_w3 = (const float*)d_in[16];
    const float* fe_b3 = (const float*)d_in[17];
    const float* fe_g  = (const float*)d_in[18];
    const float* fe_bt = (const float*)d_in[19];
    const float* ge_w1 = (const float*)d_in[20];
    const float* ge_b1 = (const float*)d_in[21];
    const float* ge_w2 = (const float*)d_in[22];
    const float* ge_b2 = (const float*)d_in[23];
    const float* ge_w3 = (const float*)d_in[24];
    const float* ge_b3 = (const float*)d_in[25];
    const float* gn_w1 = (const float*)d_in[26];
    const float* gn_b1 = (const float*)d_in[27];
    const float* gn_w2 = (const float*)d_in[28];
    const float* gn_b2 = (const float*)d_in[29];
    const float* gn_w3 = (const float*)d_in[30];
    const float* gn_b3 = (const float*)d_in[31];
    const float* de_w1 = (const float*)d_in[32];
    const float* de_b1 = (const float*)d_in[33];
    const float* de_w2 = (const float*)d_in[34];
    const float* de_b2 = (const float*)d_in[35];
    const float* de_w3 = (const float*)d_in[36];
    const float* de_b3 = (const float*)d_in[37];

    // workspace layout (~74 MB)
    char* p = (char*)d_ws;
    float* Vf   = (float*)p;  p += (size_t)N_NODE * 128 * 4;
    float* Ef   = (float*)p;  p += (size_t)N_EDGE * 128 * 4;
    float* eEs  = (float*)p;  p += (size_t)N_EDGE * 128 * 4;
    float* Yv   = (float*)p;  p += (size_t)N_NODE * 256 * 4;
    U16*  Vh    = (U16*)p;    p += (size_t)N_NODE * 128 * 2;
    U16*  Eh    = (U16*)p;    p += (size_t)N_EDGE * 128 * 2;
    U16*  Wt    = (U16*)p;    p += (size_t)WT_TOTAL * 2;
    int*  rowptr = (int*)p;   p += (size_t)(N_NODE + 4) * 4;
    int*  cursor = (int*)p;   p += (size_t)N_NODE * 4;
    int*  cnt    = (int*)p;   p += (size_t)N_NODE * 4;
    int*  spos   = (int*)p;   p += (size_t)N_EDGE * 4;

    const int gbE  = (N_EDGE + 63) / 64;    // 625 (BM=64)
    const int gbN  = (N_NODE + 31) / 32;    // 313 (BM=32)

    // ---- prep: weights, CSR
    wprep<<<566, 256, 0, stream>>>(fv_w1, fv_w2, fv_w3, fe_w1, fe_w2, fe_w3,
                                   ge_w1, ge_w2, ge_w3, gn_w1, gn_w2, gn_w3,
                                   de_w1, de_w2, Wt);
    hipMemsetAsync(cnt, 0, (size_t)N_NODE * 4, stream);
    csr_hist<<<(N_EDGE + 255) / 256, 256, 0, stream>>>(edges, cnt, N_EDGE);
    csr_scan<<<1, 256, 0, stream>>>(cnt, rowptr, cursor, N_NODE);
    csr_scatter<<<(N_EDGE + 255) / 256, 256, 0, stream>>>(edges, cursor, spos, N_EDGE);

    // ---- edge encoder (eraw fused, LN fused) -> Ef + Eh
    mlp3<A_ERAW, EPI_F, 32, 32, 64><<<gbE, 512, 0, stream>>>(
        nullptr, Wt + OFF_FE1, fe_b1, Wt + OFF_FE2, fe_b2, Wt + OFF_FE3, fe_b3,
        Eh, Ef, edges, nullptr, nullptr, nullptr, nullptr, nullptr,
        pos, nullptr, nullptr, nullptr, fe_g, fe_bt, nullptr, N_EDGE);

    // ---- node encoder (encin fused, LN fused) -> Vf + Vh
    mlp3<A_ENCIN, EPI_F, 32, 32, 32><<<gbN, 512, 0, stream>>>(
        nullptr, Wt + OFF_FV1, fv_b1, Wt + OFF_FV2, fv_b2, Wt + OFF_FV3, fv_b3,
        Vh, Vf, nullptr, nullptr, nullptr, nullptr, nullptr, nullptr,
        pos, area, info, nullptr, fv_g, fv_bt, nullptr, N_NODE);

    // ---- 15 GNN layers
    for (int l = 0; l < N_LAYER; ++l) {
        const U16* wge1 = Wt + OFF_GE1 + (size_t)l * 49152;
        yv_kernel<<<gbN, 512, 0, stream>>>(Vh, wge1, Yv, N_NODE);
        mlp3<A_EDGE, EPI_EDGE, 128, 384, 64><<<gbE, 512, 0, stream>>>(
            nullptr,
            wge1 + 256, ge_b1 + (size_t)l * 128,                 // W1e slice (k-off 256)
            Wt + OFF_GE2 + (size_t)l * 16384, ge_b2 + (size_t)l * 128,
            Wt + OFF_GE3 + (size_t)l * 16384, ge_b3 + (size_t)l * 128,
            Eh, Ef, edges, nullptr, spos, eEs, Vh, Eh,
            nullptr, nullptr, nullptr, nullptr, nullptr, nullptr, Yv, N_EDGE);
        mlp3<A_NODE, EPI_NODE, 256, 256, 32><<<gbN, 512, 0, stream>>>(
            nullptr,
            Wt + OFF_GN1 + (size_t)l * 32768, gn_b1 + (size_t)l * 128,
            Wt + OFF_GN2 + (size_t)l * 16384, gn_b2 + (size_t)l * 128,
            Wt + OFF_GN3 + (size_t)l * 16384, gn_b3 + (size_t)l * 128,
            Vh, Vf, nullptr, rowptr, spos, eEs, Vh, nullptr,
            nullptr, nullptr, nullptr, nullptr, nullptr, nullptr, nullptr, N_NODE);
    }

    // ---- decoder
    mlp3<A_BF16, EPI_DEC, 128, 128, 32><<<gbN, 512, 0, stream>>>(
        Vh, Wt + OFF_DE1, de_b1, Wt + OFF_DE2, de_b2, nullptr, de_b3,
        nullptr, (float*)d_out, nullptr, nullptr, nullptr, nullptr, nullptr, nullptr,
        nullptr, nullptr, nullptr, de_w3, nullptr, nullptr, nullptr, N_NODE);
}

// Round 6
// 1266.916 us; speedup vs baseline: 1.2601x; 1.0192x over previous
//
#include <hip/hip_runtime.h>

#define DD 128
#define N_NODE 10000
#define N_EDGE 40000
#define N_LAYER 15

typedef unsigned short U16;
typedef __attribute__((ext_vector_type(8))) short short8;
typedef __attribute__((ext_vector_type(4))) float f32x4;

enum { A_BF16 = 0, A_EDGE, A_NODE, A_ENCIN, A_ERAW };
enum { EPI_F = 0, EPI_EDGE, EPI_NODE, EPI_DEC };

// Wt layout offsets (bf16 elements), [n=128][Kpad] per matrix
#define OFF_FV1 0
#define OFF_FV2 4096
#define OFF_FV3 20480
#define OFF_FE1 36864
#define OFF_FE2 40960
#define OFF_FE3 57344
#define OFF_GE1 73728     /* stride 49152 (Kpad=384) */
#define OFF_GE2 811008    /* stride 16384 */
#define OFF_GE3 1056768
#define OFF_GN1 1302528   /* stride 32768 (Kpad=256) */
#define OFF_GN2 1794048
#define OFF_GN3 2039808
#define OFF_DE1 2285568
#define OFF_DE2 2301952
#define WT_TOTAL 2318336

static __device__ __forceinline__ U16 f2b(float f) {
    union { float f; unsigned u; } x; x.f = f;
    unsigned u = x.u;
    return (U16)((u + 0x7fffu + ((u >> 16) & 1u)) >> 16);
}
static __device__ __forceinline__ float b2f(U16 u) {
    union { unsigned u; float f; } x; x.u = ((unsigned)u) << 16;
    return x.f;
}

// workgroup barrier draining ONLY lgkmcnt: in-flight global prefetch loads
// (vmcnt) survive the barrier.
static __device__ __forceinline__ void wgb() {
    __asm__ __volatile__("s_waitcnt lgkmcnt(0)\n\ts_barrier" ::: "memory");
}

struct I4x2 { int4 a, b; };

// ---------------- weight transpose+cast: W[K][128] f32 -> Wt[n][Kpad] bf16 ----
__global__ __launch_bounds__(256)
void wprep(const float* fv1, const float* fv2, const float* fv3,
           const float* fe1, const float* fe2, const float* fe3,
           const float* ge1, const float* ge2, const float* ge3,
           const float* gn1, const float* gn2, const float* gn3,
           const float* de1, const float* de2, U16* Wt)
{
    int b = blockIdx.x;
    const float* src; U16* dst; int K, Kpad, k0;
    if      (b < 1)   { src = fv1; K = 12;  Kpad = 32;  dst = Wt + OFF_FV1; k0 = b * 32; }
    else if (b < 5)   { src = fv2; K = 128; Kpad = 128; dst = Wt + OFF_FV2; k0 = (b-1)*32; }
    else if (b < 9)   { src = fv3; K = 128; Kpad = 128; dst = Wt + OFF_FV3; k0 = (b-5)*32; }
    else if (b < 10)  { src = fe1; K = 4;   Kpad = 32;  dst = Wt + OFF_FE1; k0 = (b-9)*32; }
    else if (b < 14)  { src = fe2; K = 128; Kpad = 128; dst = Wt + OFF_FE2; k0 = (b-10)*32; }
    else if (b < 18)  { src = fe3; K = 128; Kpad = 128; dst = Wt + OFF_FE3; k0 = (b-14)*32; }
    else if (b < 198) { int r = b-18,  mi = r/12, s = r%12; src = ge1 + (size_t)mi*384*128; K = 384; Kpad = 384; dst = Wt + OFF_GE1 + (size_t)mi*49152; k0 = s*32; }
    else if (b < 258) { int r = b-198, mi = r/4,  s = r%4;  src = ge2 + (size_t)mi*16384;   K = 128; Kpad = 128; dst = Wt + OFF_GE2 + (size_t)mi*16384; k0 = s*32; }
    else if (b < 318) { int r = b-258, mi = r/4,  s = r%4;  src = ge3 + (size_t)mi*16384;   K = 128; Kpad = 128; dst = Wt + OFF_GE3 + (size_t)mi*16384; k0 = s*32; }
    else if (b < 438) { int r = b-318, mi = r/8,  s = r%8;  src = gn1 + (size_t)mi*32768;   K = 256; Kpad = 256; dst = Wt + OFF_GN1 + (size_t)mi*32768; k0 = s*32; }
    else if (b < 498) { int r = b-438, mi = r/4,  s = r%4;  src = gn2 + (size_t)mi*16384;   K = 128; Kpad = 128; dst = Wt + OFF_GN2 + (size_t)mi*16384; k0 = s*32; }
    else if (b < 558) { int r = b-498, mi = r/4,  s = r%4;  src = gn3 + (size_t)mi*16384;   K = 128; Kpad = 128; dst = Wt + OFF_GN3 + (size_t)mi*16384; k0 = s*32; }
    else if (b < 562) { src = de1; K = 128; Kpad = 128; dst = Wt + OFF_DE1; k0 = (b-558)*32; }
    else              { src = de2; K = 128; Kpad = 128; dst = Wt + OFF_DE2; k0 = (b-562)*32; }

    __shared__ float T[32][129];
    #pragma unroll
    for (int i = 0; i < 16; ++i) {
        int l = threadIdx.x + i * 256;
        int kk = l >> 7, n = l & 127;
        int kg = k0 + kk;
        T[kk][n] = (kg < K) ? src[(size_t)kg * 128 + n] : 0.f;
    }
    __syncthreads();
    int n = threadIdx.x >> 1, h = threadIdx.x & 1;
    union { U16 u[16]; int4 v[2]; } o;
    #pragma unroll
    for (int j = 0; j < 16; ++j) o.u[j] = f2b(T[h * 16 + j][n]);
    int4* d = (int4*)(dst + (size_t)n * Kpad + k0 + h * 16);
    d[0] = o.v[0]; d[1] = o.v[1];
}

// ---------------- CSR build (sender-sorted positions) ------------------------
__global__ __launch_bounds__(256)
void csr_hist(const int* __restrict__ edges, int* __restrict__ cnt, int Eg)
{
    int e = blockIdx.x * 256 + threadIdx.x;
    if (e < Eg) atomicAdd(&cnt[edges[2 * e]], 1);
}

__global__ __launch_bounds__(256)
void csr_scan(const int* __restrict__ cnt, int* __restrict__ rowptr,
              int* __restrict__ cursor, int n)
{
    __shared__ int ps[256];
    int t = threadIdx.x, base = t * 40;
    int s = 0;
    for (int j = 0; j < 40; ++j) if (base + j < n) s += cnt[base + j];
    ps[t] = s; __syncthreads();
    for (int off = 1; off < 256; off <<= 1) {
        int v = (t >= off) ? ps[t - off] : 0;
        __syncthreads();
        ps[t] += v;
        __syncthreads();
    }
    int run = ps[t] - s;   // exclusive prefix
    for (int j = 0; j < 40; ++j) {
        if (base + j < n) {
            rowptr[base + j] = run;
            cursor[base + j] = run;
            run += cnt[base + j];
        }
    }
    if (t == 255) rowptr[n] = ps[255];
}

// spos[e] = position of edge e in the sender-sorted order
__global__ __launch_bounds__(256)
void csr_scatter(const int* __restrict__ edges, int* __restrict__ cursor,
                 int* __restrict__ spos, int Eg)
{
    int e = blockIdx.x * 256 + threadIdx.x;
    if (e < Eg) spos[e] = atomicAdd(&cursor[edges[2 * e]], 1);
}

// ---------------- fused 3-layer MLP (MFMA, W-as-A, pipelined K-loop) ---------
// Exactly the R1 chassis (8 waves, LDS staging, depth-2 register prefetch,
// lgkmcnt-only barriers, spos scatter, streaming segmented sum; measured
// 1037us total) with ONE lever applied: K-chunk width 32 -> 64. This halves
// the barrier count per block (edge 25->15) and doubles the MFMA work (and
// thus the latency slack for prefetched loads) per chunk -- attacking the
// measured wall (R3 counters: all pipes <6% busy, ~2us per barrier-chained
// chunk). As/Hs overlay keeps LDS at 54272B -> 3 blocks/CU. Accumulation
// order is bit-identical to R1.
template<int ASRC, int EPI, int K1, int BM>
__global__ __launch_bounds__(512, 4)
void mlp3(const U16* __restrict__ Af,
          const U16* __restrict__ W1, const float* __restrict__ b1,
          const U16* __restrict__ W2, const float* __restrict__ b2,
          const U16* __restrict__ W3, const float* __restrict__ b3,
          U16* __restrict__ outh, float* __restrict__ outf,
          const int* __restrict__ edges, const int* __restrict__ rowptr,
          const int* __restrict__ spos, float* __restrict__ eEs,
          const U16* __restrict__ Vh, const U16* __restrict__ Ehp,
          const float* __restrict__ pos, const float* __restrict__ area,
          const float* __restrict__ info, const float* __restrict__ w3f,
          int M)
{
    constexpr int NAG = BM / 32;        // A fragments per wave (m-dir)
    __shared__ U16 Bs[2][128][72];      // W tiles, 64-wide chunks (+8 pad)
    constexpr int ASB = 2 * BM * 68 * 2;
    constexpr int HSB = BM * 132 * 2;
    constexpr int PLB = (ASB > HSB) ? ASB : HSB;
    __shared__ __align__(16) char pool[PLB];
    auto As = (U16 (*)[BM][68])pool;    // [2][BM][68] phase-1 A tiles
    auto Hs = (U16 (*)[132])pool;       // [BM][132]   overlays As (As dead)

    const int tid  = threadIdx.x;
    const int row0 = blockIdx.x * BM;
    const int wave = tid >> 6, lane = tid & 63;
    const int quad = lane >> 4, l16 = lane & 15;
    const int wm = (wave >> 2) * (16 * NAG);   // wave m-offset
    const int wn = (wave & 3) * 32;            // wave n-offset (0/32/64/96)
    // 64-wide A staging: row, 8-col unit
    const int sr8 = tid >> 3, sh8 = tid & 7;
    const int sm8 = row0 + sr8;
    const bool stg8 = (tid < BM * 8);
    const bool val8 = stg8 && (sm8 < M);
    // 32-wide A staging (K1==32 encoders)
    const int sr4 = tid >> 2, sh4 = tid & 3;
    const int sm4 = row0 + sr4;
    const bool stg4 = (tid < BM * 4);
    const bool val4 = stg4 && (sm4 < M);
    // W staging: row, 16-col unit
    const int brw = tid >> 2, bhw = tid & 3;

    int si = 0, ri = 0, jbeg = 0, jend = 0;
    if (ASRC == A_EDGE && val8) { si = edges[2 * sm8]; ri = edges[2 * sm8 + 1]; }
    if (ASRC == A_ERAW && val4) { si = edges[2 * sm4]; ri = edges[2 * sm4 + 1]; }
    if (ASRC == A_NODE && val8) { jbeg = rowptr[sm8]; jend = rowptr[sm8 + 1]; }

    f32x4 acc[2][NAG];   // [wg][ag]: n = wn+wg*16+quad*4+rg, m = wm+ag*16+l16

    auto zacc = [&] {
        #pragma unroll
        for (int i = 0; i < 2; ++i)
            #pragma unroll
            for (int j = 0; j < NAG; ++j) acc[i][j] = (f32x4)0.f;
    };

    // ---- 64-wide loaders ----------------------------------------------------
    auto ldA64 = [&](int c) -> int4 {
        int kk = c * 64 + sh8 * 8;
        if (ASRC == A_NODE && kk >= 128) {
            // segmented sum over sender-sorted e_emb rows (fp32) -> bf16
            float a[8];
            #pragma unroll
            for (int i = 0; i < 8; ++i) a[i] = 0.f;
            if (val8) {
                const float* base = eEs + (kk - 128);
                for (int j = jbeg; j < jend; ++j) {
                    const float4* r = (const float4*)(base + (size_t)j * 128);
                    float4 x0 = r[0], x1 = r[1];
                    a[0]+=x0.x; a[1]+=x0.y; a[2]+=x0.z; a[3]+=x0.w;
                    a[4]+=x1.x; a[5]+=x1.y; a[6]+=x1.z; a[7]+=x1.w;
                }
            }
            union { U16 u[8]; int4 v; } pk;
            #pragma unroll
            for (int i = 0; i < 8; ++i) pk.u[i] = f2b(a[i]);
            return pk.v;
        } else {
            const U16* s;
            if (ASRC == A_BF16)        s = Af + (size_t)sm8 * K1 + kk;
            else if (ASRC == A_EDGE) {
                if (kk < 128)      s = Vh  + (size_t)si  * 128 + kk;
                else if (kk < 256) s = Vh  + (size_t)ri  * 128 + (kk - 128);
                else               s = Ehp + (size_t)sm8 * 128 + (kk - 256);
            } else                     s = Vh  + (size_t)sm8 * 128 + kk;  // A_NODE kk<128
            return val8 ? *(const int4*)s : make_int4(0, 0, 0, 0);
        }
    };

    auto ldW64 = [&](const U16* W, int Kw, int c) -> I4x2 {
        const U16* s = W + (size_t)brw * Kw + c * 64 + bhw * 16;
        I4x2 r;
        r.a = ((const int4*)s)[0];
        r.b = ((const int4*)s)[1];
        return r;
    };

    auto wrA64 = [&](int b, int4 v) { if (stg8) *(int4*)&As[b][sr8][sh8 * 8] = v; };
    auto wrW64 = [&](int b, I4x2 w) {
        *(int4*)&Bs[b][brw][bhw * 16]     = w.a;
        *(int4*)&Bs[b][brw][bhw * 16 + 8] = w.b;
    };

    // ---- 32-wide loaders (K1==32 encoders; R1 path) -------------------------
    auto ldA32 = [&]() -> int4 {
        union { U16 u[8]; int4 v; } pk;
        #pragma unroll
        for (int j = 0; j < 8; ++j) pk.u[j] = 0;
        if (val4) {
            if (ASRC == A_ENCIN) {
                #pragma unroll
                for (int j = 0; j < 8; ++j) {
                    int col = sh4 * 8 + j;
                    float x = 0.f;
                    if (col < 3)       x = pos[3 * sm4 + col];
                    else if (col == 3) x = area[sm4];
                    else if (col < 12) x = info[col - 4];
                    pk.u[j] = f2b(x);
                }
            } else if (sh4 == 0) {     // A_ERAW
                float dx = pos[3*si]   - pos[3*ri];
                float dy = pos[3*si+1] - pos[3*ri+1];
                float dz = pos[3*si+2] - pos[3*ri+2];
                float nm = sqrtf(dx*dx + dy*dy + dz*dz);
                pk.u[0] = f2b(dx); pk.u[1] = f2b(dy);
                pk.u[2] = f2b(dz); pk.u[3] = f2b(nm);
            }
        }
        return pk.v;
    };
    auto ldW32 = [&](const U16* W) -> int4 {
        return *(const int4*)(W + (size_t)brw * 32 + bhw * 8);
    };

    // ---- MFMA steps ---------------------------------------------------------
    auto mfA = [&](int b, int nks) {   // A from As[b], W from Bs[b]
        for (int ks = 0; ks < nks; ++ks) {
            short8 wf[2], af[NAG];
            #pragma unroll
            for (int g = 0; g < 2; ++g)
                wf[g] = *(const short8*)&Bs[b][wn + g*16 + l16][ks * 32 + quad * 8];
            #pragma unroll
            for (int g = 0; g < NAG; ++g)
                af[g] = *(const short8*)&As[b][wm + g*16 + l16][ks * 32 + quad * 8];
            #pragma unroll
            for (int wg = 0; wg < 2; ++wg)
                #pragma unroll
                for (int ag = 0; ag < NAG; ++ag)
                    acc[wg][ag] = __builtin_amdgcn_mfma_f32_16x16x32_bf16(
                        wf[wg], af[ag], acc[wg][ag], 0, 0, 0);
        }
    };

    auto mfH = [&](int c, int b) {   // A from Hs 64-slice c, W from Bs[b]
        #pragma unroll
        for (int ks = 0; ks < 2; ++ks) {
            short8 wf[2], af[NAG];
            #pragma unroll
            for (int g = 0; g < 2; ++g)
                wf[g] = *(const short8*)&Bs[b][wn + g*16 + l16][ks * 32 + quad * 8];
            #pragma unroll
            for (int g = 0; g < NAG; ++g)
                af[g] = *(const short8*)&Hs[wm + g*16 + l16][c * 64 + ks * 32 + quad * 8];
            #pragma unroll
            for (int wg = 0; wg < 2; ++wg)
                #pragma unroll
                for (int ag = 0; ag < NAG; ++ag)
                    acc[wg][ag] = __builtin_amdgcn_mfma_f32_16x16x32_bf16(
                        wf[wg], af[ag], acc[wg][ag], 0, 0, 0);
        }
    };

    auto hwrite = [&](const float* bias) {
        #pragma unroll
        for (int wg = 0; wg < 2; ++wg) {
            f32x4 bv = *(const f32x4*)&bias[wn + wg*16 + quad*4];
            #pragma unroll
            for (int ag = 0; ag < NAG; ++ag) {
                int m  = wm + ag*16 + l16;
                int n0 = wn + wg*16 + quad*4;
                union { U16 u[4]; uint2 q; } pk;
                #pragma unroll
                for (int rg = 0; rg < 4; ++rg)
                    pk.u[rg] = f2b(fmaxf(acc[wg][ag][rg] + bv[rg], 0.f));
                *(uint2*)&Hs[m][n0] = pk.q;
            }
        }
    };

    // ---- phase 1 ------------------------------------------------------------
    zacc();
    if constexpr (K1 == 32) {
        wrA64(0, make_int4(0,0,0,0));   // not used; keep As defined
        if (stg4) *(int4*)&As[0][sr4][sh4 * 8] = ldA32();
        wrW64(0, I4x2{make_int4(0,0,0,0), make_int4(0,0,0,0)});
        *(int4*)&Bs[0][brw][bhw * 8] = ldW32(W1);
        wgb();
        mfA(0, 1);
        wgb();
    } else {
        constexpr int C1 = K1 / 64;
        int4 ra0, ra1; I4x2 rw0, rw1;
        ra0 = ldA64(0); rw0 = ldW64(W1, K1, 0);
        if (C1 > 1) { ra1 = ldA64(1); rw1 = ldW64(W1, K1, 1); }
        wrA64(0, ra0); wrW64(0, rw0);
        wgb();
        #pragma unroll
        for (int c = 0; c < C1; ++c) {
            if (c + 2 < C1) {                  // prefetch chunk c+2 (parity c&1)
                if ((c & 1) == 0) { ra0 = ldA64(c + 2); rw0 = ldW64(W1, K1, c + 2); }
                else              { ra1 = ldA64(c + 2); rw1 = ldW64(W1, K1, c + 2); }
            }
            if (c + 1 < C1) {                  // commit chunk c+1 to LDS
                if (((c + 1) & 1) == 0) { wrA64(0, ra0); wrW64(0, rw0); }
                else                    { wrA64(1, ra1); wrW64(1, rw1); }
            }
            mfA(c & 1, 2);
            wgb();
        }
    }

    // ---- phase 2 (W-only pipeline; A = Hs) ----------------------------------
    {
        I4x2 rw0 = ldW64(W2, 128, 0), rw1 = ldW64(W2, 128, 1);
        hwrite(b1);                            // Hs overlays As (As dead now)
        wgb();                                 // publish Hs
        zacc();
        wrW64(0, rw0);
        wgb();                                 // publish Bs[0]
        wrW64(1, rw1);
        mfH(0, 0);
        wgb();                                 // publish Bs[1]
        mfH(1, 1);
        wgb();                                 // all waves done reading Hs
    }

    if (EPI == EPI_DEC) {        // decoder: h2 -> Hs, then dot with w3f
        hwrite(b2);
        wgb();
        constexpr int TPR = 512 / BM;      // threads per row
        constexpr int CPT = 128 / TPR;     // cols per thread
        int r = tid / TPR, s8 = tid % TPR;
        int mg = row0 + r;
        float v = 0.f;
        if (mg < M) {
            const U16* hr = &Hs[r][s8 * CPT];
            const float* wr = w3f + s8 * CPT;
            #pragma unroll
            for (int j = 0; j < CPT; ++j) v += b2f(hr[j]) * wr[j];
        }
        #pragma unroll
        for (int off = 1; off < TPR; off <<= 1) v += __shfl_xor(v, off);
        if (s8 == 0 && mg < M) outf[mg] = v + b3[0];
        return;
    }

    // ---- phase 3 ------------------------------------------------------------
    {
        I4x2 rw0 = ldW64(W3, 128, 0), rw1 = ldW64(W3, 128, 1);
        hwrite(b2);
        wgb();
        zacc();
        wrW64(0, rw0);
        wgb();
        wrW64(1, rw1);
        mfH(0, 0);
        wgb();
        mfH(1, 1);
        // no trailing barrier needed: epilogue reads only registers
    }

    // ---- epilogue -----------------------------------------------------------
    f32x4 bvs[2];
    #pragma unroll
    for (int wg = 0; wg < 2; ++wg)
        bvs[wg] = *(const f32x4*)&b3[wn + wg*16 + quad*4];
    #pragma unroll
    for (int ag = 0; ag < NAG; ++ag) {
        int mg = row0 + wm + ag*16 + l16;
        if (mg >= M) continue;
        int sp = 0;
        if (EPI == EPI_EDGE) sp = spos[mg];
        #pragma unroll
        for (int wg = 0; wg < 2; ++wg) {
            int n0 = wn + wg*16 + quad*4;
            f32x4 v;
            #pragma unroll
            for (int rg = 0; rg < 4; ++rg) v[rg] = acc[wg][ag][rg] + bvs[wg][rg];
            size_t o = (size_t)mg * 128 + n0;
            if (EPI == EPI_F) {
                *(f32x4*)&outf[o] = v;
            } else {
                f32x4 c = *(f32x4*)&outf[o];
                c += v;
                *(f32x4*)&outf[o] = c;
                union { U16 u[4]; uint2 q; } pk;
                #pragma unroll
                for (int rg = 0; rg < 4; ++rg) pk.u[rg] = f2b(c[rg]);
                *(uint2*)&outh[o] = pk.q;
                if (EPI == EPI_EDGE)
                    *(f32x4*)&eEs[(size_t)sp * 128 + n0] = v;   // sorted e_emb
            }
        }
    }
}

// in-place LayerNorm over D=128 on fp32 master + bf16 mirror
__global__ __launch_bounds__(256)
void ln_kernel(float* __restrict__ X, const float* __restrict__ g,
               const float* __restrict__ b, U16* __restrict__ Xh, int rows)
{
    int row  = blockIdx.x * 4 + (threadIdx.x >> 6);
    int lane = threadIdx.x & 63;
    if (row >= rows) return;
    float x0 = X[row * DD + lane];
    float x1 = X[row * DD + 64 + lane];
    float s = x0 + x1, q = x0 * x0 + x1 * x1;
    #pragma unroll
    for (int off = 32; off; off >>= 1) {
        s += __shfl_xor(s, off);
        q += __shfl_xor(q, off);
    }
    float mu  = s * (1.f / 128.f);
    float var = q * (1.f / 128.f) - mu * mu;
    float inv = rsqrtf(var + 1e-5f);
    float y0 = (x0 - mu) * inv * g[lane]      + b[lane];
    float y1 = (x1 - mu) * inv * g[64 + lane] + b[64 + lane];
    X[row * DD + lane]       = y0;
    X[row * DD + 64 + lane]  = y1;
    Xh[row * DD + lane]      = f2b(y0);
    Xh[row * DD + 64 + lane] = f2b(y1);
}

extern "C" void kernel_launch(void* const* d_in, const int* in_sizes, int n_in,
                              void* d_out, int out_size, void* d_ws, size_t ws_size,
                              hipStream_t stream)
{
    (void)in_sizes; (void)n_in; (void)out_size; (void)ws_size;

    const float* pos   = (const float*)d_in[0];
    const float* area  = (const float*)d_in[1];
    const float* info  = (const float*)d_in[2];
    const int*   edges = (const int*)d_in[3];
    const float* fv_w1 = (const float*)d_in[4];
    const float* fv_b1 = (const float*)d_in[5];
    const float* fv_w2 = (const float*)d_in[6];
    const float* fv_b2 = (const float*)d_in[7];
    const float* fv_w3 = (const float*)d_in[8];
    const float* fv_b3 = (const float*)d_in[9];
    const float* fv_g  = (const float*)d_in[10];
    const float* fv_bt = (const float*)d_in[11];
    const float* fe_w1 = (const float*)d_in[12];
    const float* fe_b1 = (const float*)d_in[13];
    const float* fe_w2 = (const float*)d_in[14];
    const float* fe_b2 = (const float*)d_in[15];
    const float* fe_w3 = (const float*)d_in[16];
    const float* fe_b3 = (const float*)d_in[17];
    const float* fe_g  = (const float*)d_in[18];
    const float* fe_bt = (const float*)d_in[19];
    const float* ge_w1 = (const float*)d_in[20];
    const float* ge_b1 = (const float*)d_in[21];
    const float* ge_w2 = (const float*)d_in[22];
    const float* ge_b2 = (const float*)d_in[23];
    const float* ge_w3 = (const float*)d_in[24];
    const float* ge_b3 = (const float*)d_in[25];
    const float* gn_w1 = (const float*)d_in[26];
    const float* gn_b1 = (const float*)d_in[27];
    const float* gn_w2 = (const float*)d_in[28];
    const float* gn_b2 = (const float*)d_in[29];
    const float* gn_w3 = (const float*)d_in[30];
    const float* gn_b3 = (const float*)d_in[31];
    const float* de_w1 = (const float*)d_in[32];
    const float* de_b1 = (const float*)d_in[33];
    const float* de_w2 = (const float*)d_in[34];
    const float* de_b2 = (const float*)d_in[35];
    const float* de_w3 = (const float*)d_in[36];
    const float* de_b3 = (const float*)d_in[37];

    // workspace layout (~64 MB)
    char* p = (char*)d_ws;
    float* Vf   = (float*)p;  p += (size_t)N_NODE * 128 * 4;
    float* Ef   = (float*)p;  p += (size_t)N_EDGE * 128 * 4;
    float* eEs  = (float*)p;  p += (size_t)N_EDGE * 128 * 4;
    U16*  Vh    = (U16*)p;    p += (size_t)N_NODE * 128 * 2;
    U16*  Eh    = (U16*)p;    p += (size_t)N_EDGE * 128 * 2;
    U16*  Wt    = (U16*)p;    p += (size_t)WT_TOTAL * 2;
    int*  rowptr = (int*)p;   p += (size_t)(N_NODE + 4) * 4;
    int*  cursor = (int*)p;   p += (size_t)N_NODE * 4;
    int*  cnt    = (int*)p;   p += (size_t)N_NODE * 4;
    int*  spos   = (int*)p;   p += (size_t)N_EDGE * 4;

    const int gbE = (N_EDGE + 63) / 64;   // 625 (BM=64)
    const int gbN = (N_NODE + 31) / 32;   // 313 (BM=32)

    // ---- prep: weights, CSR
    wprep<<<566, 256, 0, stream>>>(fv_w1, fv_w2, fv_w3, fe_w1, fe_w2, fe_w3,
                                   ge_w1, ge_w2, ge_w3, gn_w1, gn_w2, gn_w3,
                                   de_w1, de_w2, Wt);
    hipMemsetAsync(cnt, 0, (size_t)N_NODE * 4, stream);
    csr_hist<<<(N_EDGE + 255) / 256, 256, 0, stream>>>(edges, cnt, N_EDGE);
    csr_scan<<<1, 256, 0, stream>>>(cnt, rowptr, cursor, N_NODE);
    csr_scatter<<<(N_EDGE + 255) / 256, 256, 0, stream>>>(edges, cursor, spos, N_EDGE);

    // ---- edge encoder (eraw fused) -> Ef; LN -> Ef + Eh
    mlp3<A_ERAW, EPI_F, 32, 64><<<gbE, 512, 0, stream>>>(
        nullptr, Wt + OFF_FE1, fe_b1, Wt + OFF_FE2, fe_b2, Wt + OFF_FE3, fe_b3,
        nullptr, Ef, edges, nullptr, nullptr, nullptr, nullptr, nullptr,
        pos, nullptr, nullptr, nullptr, N_EDGE);
    ln_kernel<<<(N_EDGE + 3) / 4, 256, 0, stream>>>(Ef, fe_g, fe_bt, Eh, N_EDGE);

    // ---- node encoder (encin fused) -> Vf; LN -> Vf + Vh
    mlp3<A_ENCIN, EPI_F, 32, 32><<<gbN, 512, 0, stream>>>(
        nullptr, Wt + OFF_FV1, fv_b1, Wt + OFF_FV2, fv_b2, Wt + OFF_FV3, fv_b3,
        nullptr, Vf, nullptr, nullptr, nullptr, nullptr, nullptr, nullptr,
        pos, area, info, nullptr, N_NODE);
    ln_kernel<<<(N_NODE + 3) / 4, 256, 0, stream>>>(Vf, fv_g, fv_bt, Vh, N_NODE);

    // ---- 15 GNN layers
    for (int l = 0; l < N_LAYER; ++l) {
        mlp3<A_EDGE, EPI_EDGE, 384, 64><<<gbE, 512, 0, stream>>>(
            nullptr,
            Wt + OFF_GE1 + (size_t)l * 49152, ge_b1 + (size_t)l * 128,
            Wt + OFF_GE2 + (size_t)l * 16384, ge_b2 + (size_t)l * 128,
            Wt + OFF_GE3 + (size_t)l * 16384, ge_b3 + (size_t)l * 128,
            Eh, Ef, edges, nullptr, spos, eEs, Vh, Eh,
            nullptr, nullptr, nullptr, nullptr, N_EDGE);
        mlp3<A_NODE, EPI_NODE, 256, 32><<<gbN, 512, 0, stream>>>(
            nullptr,
            Wt + OFF_GN1 + (size_t)l * 32768, gn_b1 + (size_t)l * 128,
            Wt + OFF_GN2 + (size_t)l * 16384, gn_b2 + (size_t)l * 128,
            Wt + OFF_GN3 + (size_t)l * 16384, gn_b3 + (size_t)l * 128,
            Vh, Vf, nullptr, rowptr, nullptr, eEs, Vh, nullptr,
            nullptr, nullptr, nullptr, nullptr, N_NODE);
    }

    // ---- decoder
    mlp3<A_BF16, EPI_DEC, 128, 32><<<gbN, 512, 0, stream>>>(
        Vh, Wt + OFF_DE1, de_b1, Wt + OFF_DE2, de_b2, nullptr, de_b3,
        nullptr, (float*)d_out, nullptr, nullptr, nullptr, nullptr, nullptr, nullptr,
        nullptr, nullptr, nullptr, de_w3, N_NODE);
}